// Round 8
// baseline (1375.901 us; speedup 1.0000x reference)
//
#include <hip/hip_runtime.h>
#include <hip/hip_bf16.h>

// BinaryLinear: C[M,N] = (x[M,K] @ sign(W)[N,K]^T) * scale + bias
// M=8192 K=4096 N=16384 fp32. Binarize W -> +-1 bf16, round x -> bf16,
// bf16 MFMA GEMM. Round 8: R3 skeleton (2 substeps/K-tile, counted vmcnt(4),
// proven ledger) with the substep body INTERLEAVED: 6 upfront ds_reads, then
// 6 x {4 MFMA + 1 ds_read}, then 8 tail MFMA, pinned via sched_group_barrier
// (T19) so the LDS port runs during MFMA issue stalls (AITER-style 1:1-ish
// interleave). No lgkmcnt(0)/sched_barrier(0)/setprio in the loop.

typedef __attribute__((ext_vector_type(4))) float f32x4;
typedef __attribute__((ext_vector_type(8))) short s16x8;
typedef __attribute__((ext_vector_type(4))) unsigned int u32x4;

#define AS1(p) ((const __attribute__((address_space(1))) void*)(p))
#define AS3(p) ((__attribute__((address_space(3))) void*)(p))

__device__ __forceinline__ unsigned short f2bf(float f) {
  unsigned u = __float_as_uint(f);
  u += 0x7FFFu + ((u >> 16) & 1u);
  return (unsigned short)(u >> 16);
}

__global__ void __launch_bounds__(256) cvt_f32_bf16(const float* __restrict__ in,
                                                    unsigned short* __restrict__ out,
                                                    int n8) {
  int i = blockIdx.x * 256 + threadIdx.x;
  const int stride = gridDim.x * 256;
  for (; i < n8; i += stride) {
    const f32x4* p = (const f32x4*)in + (size_t)i * 2;
    f32x4 v0 = p[0], v1 = p[1];
    s16x8 o;
    o[0] = (short)f2bf(v0[0]); o[1] = (short)f2bf(v0[1]);
    o[2] = (short)f2bf(v0[2]); o[3] = (short)f2bf(v0[3]);
    o[4] = (short)f2bf(v1[0]); o[5] = (short)f2bf(v1[1]);
    o[6] = (short)f2bf(v1[2]); o[7] = (short)f2bf(v1[3]);
    *(s16x8*)(out + (size_t)i * 8) = o;
  }
}

__global__ void __launch_bounds__(256) bin_f32_bf16(const unsigned int* __restrict__ in,
                                                    unsigned short* __restrict__ out,
                                                    int n8) {
  int i = blockIdx.x * 256 + threadIdx.x;
  const int stride = gridDim.x * 256;
  for (; i < n8; i += stride) {
    const u32x4* p = (const u32x4*)in + (size_t)i * 2;
    u32x4 v0 = p[0], v1 = p[1];
    s16x8 o;  // bf16 +-1.0 from fp32 sign bit
    o[0] = (short)(0x3F80u | ((v0[0] >> 16) & 0x8000u));
    o[1] = (short)(0x3F80u | ((v0[1] >> 16) & 0x8000u));
    o[2] = (short)(0x3F80u | ((v0[2] >> 16) & 0x8000u));
    o[3] = (short)(0x3F80u | ((v0[3] >> 16) & 0x8000u));
    o[4] = (short)(0x3F80u | ((v1[0] >> 16) & 0x8000u));
    o[5] = (short)(0x3F80u | ((v1[1] >> 16) & 0x8000u));
    o[6] = (short)(0x3F80u | ((v1[2] >> 16) & 0x8000u));
    o[7] = (short)(0x3F80u | ((v1[3] >> 16) & 0x8000u));
    *(s16x8*)(out + (size_t)i * 8) = o;
  }
}

// ---------------------------------------------------------------------------
// 256x256 tile, BK=64, 512 threads = 8 waves (2M x 4N), wave tile 128x64.
// LDS (128 KiB): buf{0,1} x op{A,B} x Khalf{0,1} regions of 256 rows x 64 B.
//   byte = buf*65536 + op*32768 + h*16384 + row*64 + (kc ^ ((row>>1)&3))*16
// Stage: global_load_lds w=16, linear dest, inverse-swizzled source.
// Per substep (K-half): [4 staging loads][b0..3,a00,a01 reads]
// [6 x {4 MFMA, 1 ds_read}][8 MFMA][vmcnt(4)][barrier], interleave pinned
// with sched_group_barrier(MFMA=0x8 / DS_READ=0x100). R3's staging ledger.
// ---------------------------------------------------------------------------

#define WAITV4() asm volatile("s_waitcnt vmcnt(4)" ::: "memory")
#define WAITV0() asm volatile("s_waitcnt vmcnt(0)" ::: "memory")
#define BAR()    __builtin_amdgcn_s_barrier()
#define SGB(m, n) __builtin_amdgcn_sched_group_barrier((m), (n), 0)

#define LDSB ((const char*)lds)
#define RD(ofs) (*(const s16x8*)(LDSB + bufR + (ofs)))

// 4 MFMAs: m-subtile q (q<4 -> a0 rows, q>=4 -> a1 rows) times b[0..3]
#define QUAD(q, areg)                                                          \
  do {                                                                         \
    _Pragma("unroll") for (int nj = 0; nj < 4; ++nj)                           \
        acc[(q)][nj] = __builtin_amdgcn_mfma_f32_16x16x32_bf16(                \
            (areg), b[nj], acc[(q)][nj], 0, 0, 0);                             \
  } while (0)

#define SUBSTEP_I(hOfs)                                                        \
  do {                                                                         \
    s16x8 b[4], a0[4], a1[4];                                                  \
    b[0] = RD(rdB + (hOfs));                                                   \
    b[1] = RD(rdB + (hOfs) + 1024);                                            \
    b[2] = RD(rdB + (hOfs) + 2048);                                            \
    b[3] = RD(rdB + (hOfs) + 3072);                                            \
    a0[0] = RD(rdA + (hOfs));                                                  \
    a0[1] = RD(rdA + (hOfs) + 1024);                                           \
    QUAD(0, a0[0]); a0[2] = RD(rdA + (hOfs) + 2048);                           \
    QUAD(1, a0[1]); a0[3] = RD(rdA + (hOfs) + 3072);                           \
    QUAD(2, a0[2]); a1[0] = RD(rdA + (hOfs) + 4096);                           \
    QUAD(3, a0[3]); a1[1] = RD(rdA + (hOfs) + 5120);                           \
    QUAD(4, a1[0]); a1[2] = RD(rdA + (hOfs) + 6144);                           \
    QUAD(5, a1[1]); a1[3] = RD(rdA + (hOfs) + 7168);                           \
    QUAD(6, a1[2]);                                                            \
    QUAD(7, a1[3]);                                                            \
    /* pin the interleave: 6 reads, then 6x(4 MFMA + 1 read), then 8 MFMA */   \
    SGB(0x100, 6);                                                             \
    SGB(0x8, 4); SGB(0x100, 1);                                                \
    SGB(0x8, 4); SGB(0x100, 1);                                                \
    SGB(0x8, 4); SGB(0x100, 1);                                                \
    SGB(0x8, 4); SGB(0x100, 1);                                                \
    SGB(0x8, 4); SGB(0x100, 1);                                                \
    SGB(0x8, 4); SGB(0x100, 1);                                                \
    SGB(0x8, 8);                                                               \
  } while (0)

#define STAGE(srcbase, bufo, op, h, koff)                                      \
  do {                                                                         \
    __builtin_amdgcn_global_load_lds(                                          \
        AS1((srcbase) + (koff) + (h) * 64),                                    \
        AS3((char*)lds + (bufo) + (op) * 32768 + (h) * 16384 + wv * 1024),     \
        16, 0, 0);                                                             \
    __builtin_amdgcn_global_load_lds(                                          \
        AS1((srcbase) + 128 * Kb + (koff) + (h) * 64),                         \
        AS3((char*)lds + (bufo) + (op) * 32768 + (h) * 16384 + wv * 1024 +     \
            8192),                                                             \
        16, 0, 0);                                                             \
  } while (0)

__global__ void __launch_bounds__(512, 2)
gemm256(const unsigned short* __restrict__ A, const unsigned short* __restrict__ B,
        const float* __restrict__ scale, const float* __restrict__ bias,
        float* __restrict__ C, const int M, const int N, const int K) {
  __shared__ unsigned short lds[65536];  // 128 KiB
  const int tid = threadIdx.x;
  const int lane = tid & 63;
  const int wv = tid >> 6;   // 0..7
  const int wm = wv >> 2;    // 0..1
  const int wn = wv & 3;     // 0..3
  const int lr = lane & 15, lk = lane >> 4;

  // XCD-aware swizzle (bijective: nwg % 8 == 0 for our shape)
  const int mt = M >> 8, nt = N >> 8;
  const int nwg = mt * nt;
  const int orig = blockIdx.x;
  const int wg = (nwg & 7) ? orig : ((orig & 7) * (nwg >> 3) + (orig >> 3));
  const int bm = wg % mt;
  const int bn = wg / mt;
  const int rA0 = bm * 256, rB0 = bn * 256;

  // ds_read per-thread byte bases (swizzled column is per-thread constant)
  const int swc = (lk ^ ((lr >> 1) & 3)) * 16;
  const int rdA = (wm * 128 + lr) * 64 + swc;
  const int rdB = 32768 + (wn * 64 + lr) * 64 + swc;

  // stage per-thread source base (inverse-swizzled)
  const int kc2 = (lane & 3) ^ ((lane >> 3) & 3);
  const long Kb = (long)K * 2;
  const char* sA0 = (const char*)A + (long)(rA0 + wv * 16 + (lane >> 2)) * Kb + kc2 * 16;
  const char* sB0 = (const char*)B + (long)(rB0 + wv * 16 + (lane >> 2)) * Kb + kc2 * 16;

  f32x4 acc[8][4] = {};
  const int NT = K >> 6;

  // prologue: stage tile 0 into buf0, groups [A-h0,B-h0] then [A-h1,B-h1]
  STAGE(sA0, 0, 0, 0, 0);
  STAGE(sB0, 0, 1, 0, 0);
  STAGE(sA0, 0, 0, 1, 0);
  STAGE(sB0, 0, 1, 1, 0);
  WAITV4();  // h0 landed; h1 (4 loads) in flight
  BAR();

  for (int t = 0; t < NT - 1; ++t) {
    const int bufR = (t & 1) * 65536;
    const int bufW = 65536 - bufR;
    const long koff = (long)(t + 1) * 128;

    // ---- substep h=0: reads buf[t].h0 (published), stages h0(t+1) ----
    STAGE(sA0, bufW, 0, 0, koff);
    STAGE(sB0, bufW, 1, 0, koff);
    SUBSTEP_I(0);
    WAITV4();  // retire h1(t); keep h0(t+1) in flight
    BAR();     // publish h1(t)

    // ---- substep h=1: reads buf[t].h1, stages h1(t+1) ----
    STAGE(sA0, bufW, 0, 1, koff);
    STAGE(sB0, bufW, 1, 1, koff);
    SUBSTEP_I(16384);
    WAITV4();  // retire h0(t+1); keep h1(t+1) in flight
    BAR();     // publish h0(t+1)
  }

  // peeled last tile (no stages)
  {
    const int bufR = ((NT - 1) & 1) * 65536;
    SUBSTEP_I(0);
    WAITV0();  // h1(NT-1) landed (nothing else outstanding)
    BAR();
    SUBSTEP_I(16384);
  }

  // epilogue: C = acc*scale + bias ; C/D layout: col=lane&15, row=(lane>>4)*4+reg
  const float s = scale[0];
  const int n0 = rB0 + wn * 64 + lr;
  float bb[4];
#pragma unroll
  for (int nj = 0; nj < 4; ++nj) bb[nj] = bias[n0 + nj * 16];
#pragma unroll
  for (int mi = 0; mi < 8; ++mi) {
#pragma unroll
    for (int rg = 0; rg < 4; ++rg) {
      float* crow = C + (size_t)(rA0 + wm * 128 + mi * 16 + lk * 4 + rg) * N + n0;
#pragma unroll
      for (int nj = 0; nj < 4; ++nj)
        crow[nj * 16] = acc[mi][nj][rg] * s + bb[nj];
    }
  }
}

// ---------------- round-1 128x128 kernel kept as fallback ----------------
template <bool ABF, bool BBF>
__global__ void __launch_bounds__(256, 2)
gemm_bin(const void* __restrict__ Ap, const void* __restrict__ Bp,
         const float* __restrict__ scale, const float* __restrict__ bias,
         float* __restrict__ C, const int M, const int N, const int K) {
  __shared__ unsigned short As[128 * 64];
  __shared__ unsigned short Bs[128 * 64];
  const int tid = threadIdx.x;
  const int lane = tid & 63;
  const int wv = tid >> 6;
  const int wm = wv >> 1, wn = wv & 1;
  const int bn = blockIdx.x, bm = blockIdx.y;
  const int lr = lane & 15, lk = lane >> 4;
  f32x4 acc[4][4] = {};
  const int rA0 = bm * 128, rB0 = bn * 128;

  for (int k0 = 0; k0 < K; k0 += 64) {
    if constexpr (ABF) {
      const unsigned short* Ag = (const unsigned short*)Ap;
#pragma unroll
      for (int i = 0; i < 4; ++i) {
        const int cbase = i * 256 + wv * 64;
        const int c = cbase + lane;
        const int row = c >> 3, kc = c & 7;
        const int kcs = kc ^ (row & 7);
        const unsigned short* src = Ag + (size_t)(rA0 + row) * K + (k0 + kcs * 8);
        __builtin_amdgcn_global_load_lds(AS1(src), AS3(&As[cbase * 8]), 16, 0, 0);
      }
    } else {
      const float* Ag = (const float*)Ap;
#pragma unroll
      for (int i = 0; i < 4; ++i) {
        const int c = i * 256 + tid;
        const int row = c >> 3, kc = c & 7;
        const f32x4* src = (const f32x4*)(Ag + (size_t)(rA0 + row) * K + (k0 + kc * 8));
        f32x4 v0 = src[0], v1 = src[1];
        s16x8 o;
        o[0] = (short)f2bf(v0[0]); o[1] = (short)f2bf(v0[1]);
        o[2] = (short)f2bf(v0[2]); o[3] = (short)f2bf(v0[3]);
        o[4] = (short)f2bf(v1[0]); o[5] = (short)f2bf(v1[1]);
        o[6] = (short)f2bf(v1[2]); o[7] = (short)f2bf(v1[3]);
        *(s16x8*)&As[(row * 8 + (kc ^ (row & 7))) * 8] = o;
      }
    }
    if constexpr (BBF) {
      const unsigned short* Bg = (const unsigned short*)Bp;
#pragma unroll
      for (int i = 0; i < 4; ++i) {
        const int cbase = i * 256 + wv * 64;
        const int c = cbase + lane;
        const int row = c >> 3, kc = c & 7;
        const int kcs = kc ^ (row & 7);
        const unsigned short* src = Bg + (size_t)(rB0 + row) * K + (k0 + kcs * 8);
        __builtin_amdgcn_global_load_lds(AS1(src), AS3(&Bs[cbase * 8]), 16, 0, 0);
      }
    } else {
      const unsigned int* Bg = (const unsigned int*)Bp;
#pragma unroll
      for (int i = 0; i < 4; ++i) {
        const int c = i * 256 + tid;
        const int row = c >> 3, kc = c & 7;
        const u32x4* src = (const u32x4*)(Bg + (size_t)(rB0 + row) * K + (k0 + kc * 8));
        u32x4 v0 = src[0], v1 = src[1];
        s16x8 o;
        o[0] = (short)(0x3F80u | ((v0[0] >> 16) & 0x8000u));
        o[1] = (short)(0x3F80u | ((v0[1] >> 16) & 0x8000u));
        o[2] = (short)(0x3F80u | ((v0[2] >> 16) & 0x8000u));
        o[3] = (short)(0x3F80u | ((v0[3] >> 16) & 0x8000u));
        o[4] = (short)(0x3F80u | ((v1[0] >> 16) & 0x8000u));
        o[5] = (short)(0x3F80u | ((v1[1] >> 16) & 0x8000u));
        o[6] = (short)(0x3F80u | ((v1[2] >> 16) & 0x8000u));
        o[7] = (short)(0x3F80u | ((v1[3] >> 16) & 0x8000u));
        *(s16x8*)&Bs[(row * 8 + (kc ^ (row & 7))) * 8] = o;
      }
    }
    __syncthreads();
#pragma unroll
    for (int ks = 0; ks < 2; ++ks) {
      s16x8 a[4], b[4];
#pragma unroll
      for (int mi = 0; mi < 4; ++mi) {
        const int row = wm * 64 + mi * 16 + lr;
        const int kc = ks * 4 + lk;
        a[mi] = *(const s16x8*)&As[(row * 8 + (kc ^ (row & 7))) * 8];
      }
#pragma unroll
      for (int ni = 0; ni < 4; ++ni) {
        const int row = wn * 64 + ni * 16 + lr;
        const int kc = ks * 4 + lk;
        b[ni] = *(const s16x8*)&Bs[(row * 8 + (kc ^ (row & 7))) * 8];
      }
#pragma unroll
      for (int mi = 0; mi < 4; ++mi)
#pragma unroll
        for (int ni = 0; ni < 4; ++ni)
          acc[mi][ni] = __builtin_amdgcn_mfma_f32_16x16x32_bf16(a[mi], b[ni],
                                                               acc[mi][ni], 0, 0, 0);
    }
    __syncthreads();
  }

  const float s = scale[0];
  const int n0 = rB0 + wn * 64 + lr;
  const int m0 = rA0 + wm * 64 + lk * 4;
  float bb[4];
#pragma unroll
  for (int ni = 0; ni < 4; ++ni) bb[ni] = bias[n0 + ni * 16];
#pragma unroll
  for (int mi = 0; mi < 4; ++mi) {
#pragma unroll
    for (int r = 0; r < 4; ++r) {
      float* crow = C + (size_t)(m0 + mi * 16 + r) * N + n0;
#pragma unroll
      for (int ni = 0; ni < 4; ++ni)
        crow[ni * 16] = acc[mi][ni][r] * s + bb[ni];
    }
  }
}

extern "C" void kernel_launch(void* const* d_in, const int* in_sizes, int n_in,
                              void* d_out, int out_size, void* d_ws, size_t ws_size,
                              hipStream_t stream) {
  const float* x = (const float*)d_in[0];
  const float* w = (const float*)d_in[1];
  const float* scale = (const float*)d_in[2];
  const float* bias = (const float*)d_in[3];
  float* out = (float*)d_out;

  const int K = 4096;
  const int M = in_sizes[0] / K;  // 8192
  const int N = in_sizes[3];      // 16384

  const size_t needA = (size_t)M * K * sizeof(unsigned short);
  const size_t needB = (size_t)N * K * sizeof(unsigned short);

  if (ws_size >= needA + needB && (M % 256) == 0 && (N % 256) == 0 && (K % 256) == 0) {
    unsigned short* xb = (unsigned short*)d_ws;
    unsigned short* wb = (unsigned short*)((char*)d_ws + needA);
    cvt_f32_bf16<<<2048, 256, 0, stream>>>(x, xb, (M * K) / 8);
    bin_f32_bf16<<<2048, 256, 0, stream>>>((const unsigned int*)w, wb, (N * K) / 8);
    gemm256<<<dim3((M / 256) * (N / 256)), 512, 0, stream>>>(xb, wb, scale, bias,
                                                             out, M, N, K);
  } else if (ws_size >= needA + needB) {
    unsigned short* xb = (unsigned short*)d_ws;
    unsigned short* wb = (unsigned short*)((char*)d_ws + needA);
    cvt_f32_bf16<<<2048, 256, 0, stream>>>(x, xb, (M * K) / 8);
    bin_f32_bf16<<<2048, 256, 0, stream>>>((const unsigned int*)w, wb, (N * K) / 8);
    gemm_bin<true, true><<<dim3(N / 128, M / 128), 256, 0, stream>>>(
        xb, wb, scale, bias, out, M, N, K);
  } else if (ws_size >= needB) {
    unsigned short* wb = (unsigned short*)d_ws;
    bin_f32_bf16<<<2048, 256, 0, stream>>>((const unsigned int*)w, wb, (N * K) / 8);
    gemm_bin<false, true><<<dim3(N / 128, M / 128), 256, 0, stream>>>(
        x, wb, scale, bias, out, M, N, K);
  } else {
    gemm_bin<false, false><<<dim3(N / 128, M / 128), 256, 0, stream>>>(
        x, w, scale, bias, out, M, N, K);
  }
}